// Round 10
// baseline (208.322 us; speedup 1.0000x reference)
//
#include <hip/hip_runtime.h>
#include <hip/hip_bf16.h>
#include <stdint.h>

#define B_   4
#define C_   256
#define C8_  32
#define HW_  4096
#define ROWS_ 320   // 32 Q + 32 K + 256 V composite rows
#define L2E  1.4426950408889634f

typedef __attribute__((ext_vector_type(8)))  short  short8;
typedef __attribute__((ext_vector_type(8)))  ushort us8;
typedef __attribute__((ext_vector_type(2)))  float  f32x2;
typedef __attribute__((ext_vector_type(16))) float  f32x16;

// ---- workspace layout (bytes) ----
#define WT_OFF    0
#define BALL_OFF  (256*320*4)
#define Q_OFF     (BALL_OFF + 1280)
#define KT_OFF    (Q_OFF  + B_*HW_*C8_*2)
#define V_OFF     (KT_OFF + B_*HW_*C8_*2)

__device__ __forceinline__ ushort f2bf(float f) {
    union { float f; uint32_t u; } v; v.f = f;
    uint32_t u = v.u;
    uint32_t r = u + 0x7fffu + ((u >> 16) & 1u);  // RNE
    return (ushort)(r >> 16);
}
__device__ __forceinline__ uint32_t pktr(float lo, float hi) {
    union { float f; uint32_t u; } a, b; a.f = lo; b.f = hi;
    return __builtin_amdgcn_perm(b.u, a.u, 0x07060302u);  // 1-instr trunc pack
}
// Packed Schraudolph exp2 on a pair: v_pk_fma + v_pk_max + 2 cvt + 1 perm.
__device__ __forceinline__ uint32_t fexp2_pk(float s0, float s1, f32x2& e01) {
    f32x2 s = {s0, s1};
    f32x2 y = __builtin_elementwise_fma(s, (f32x2)(8388608.0f),
                                        (f32x2)(1064992506.0f)); // (127-0.043)*2^23
    y = __builtin_elementwise_max(y, (f32x2)(0.0f));
    union { int i; float f; } c0, c1;
    c0.i = (int)y.x;  c1.i = (int)y.y;
    e01.x = c0.f;  e01.y = c1.f;
    return __builtin_amdgcn_perm((uint32_t)c1.i, (uint32_t)c0.i, 0x07060302u);
}

// ---------------- kernel 1: fold conv into weights (bf16, A-frag-major) ----
__global__ __launch_bounds__(256) void k_setup(
    const float* __restrict__ conv_w, const float* __restrict__ conv_b,
    const float* __restrict__ q_w, const float* __restrict__ q_b,
    const float* __restrict__ k_w, const float* __restrict__ k_b,
    const float* __restrict__ v_w, const float* __restrict__ v_b,
    ushort* __restrict__ wbf, float* __restrict__ ball)
{
    int r = blockIdx.x;        // 0..319 composite row
    int c = threadIdx.x;       // 0..255 input channel (k)
    const float* wrow;
    float bias;
    if (r < 32)       { wrow = q_w + r*32;      bias = q_b[r];      }
    else if (r < 64)  { wrow = k_w + (r-32)*32; bias = k_b[r-32];   }
    else              { wrow = v_w + (r-64)*32; bias = v_b[r-64];   }
    float acc = 0.f;
    #pragma unroll
    for (int d = 0; d < 32; ++d) acc += wrow[d] * conv_w[d*C_ + c];
    float scale = (r < 32) ? L2E : 1.0f;       // fold log2(e) into Q
    int lanew = (r & 31) + 32*((c >> 3) & 1);
    int fidx  = (c >> 4)*10 + (r >> 5);        // [kc][rowblk]
    wbf[fidx*512 + lanew*8 + (c & 7)] = f2bf(acc * scale);
    if (c == 0) {
        float bb = bias;
        #pragma unroll
        for (int d = 0; d < 32; ++d) bb += wrow[d] * conv_b[d];
        ball[r] = bb * scale;
    }
}

// ---------------- kernel 2: Q/Kt/V projection via MFMA + LDS transpose -----
// grid = B*128, 320 thr (5 waves = 320 rows x 32 n). R8-measured version:
// bulk x-tile stage via global_load_lds (was 5x redundant strided loads).
__global__ __launch_bounds__(320) void k_qkv(
    const float* __restrict__ x, const ushort* __restrict__ wbf,
    const float* __restrict__ ball,
    ushort* __restrict__ qg, ushort* __restrict__ ktg, ushort* __restrict__ vg)
{
    __shared__ float  xt[256*32];     // 32KB staged x tile [c(256)][n(32)]
    __shared__ ushort tr[5][32*40];   // per-wave 32x32 transpose tile

    int blk = blockIdx.x;
    int b  = blk >> 7;
    int nt = blk & 127;                // n-tile index (32 cols)
    int n0 = nt * 32;
    int t = threadIdx.x;
    int w = t >> 6, lane = t & 63;
    int l31 = lane & 31, h = lane >> 5;

    const float* xsrc = x + (size_t)b*C_*HW_ + n0;
    if (w < 4) {
        #pragma unroll
        for (int i = 0; i < 8; ++i) {
            int chunk = w*8 + i;
            const float* src = xsrc + (size_t)(chunk*8 + (lane >> 3))*HW_
                               + (lane & 7)*4;
            __builtin_amdgcn_global_load_lds(
                (const __attribute__((address_space(1))) uint32_t*)src,
                (__attribute__((address_space(3))) uint32_t*)&xt[chunk*256],
                16, 0, 0);
        }
    }
    __syncthreads();

    f32x16 acc[2];
    acc[0] = (f32x16)(0.f);
    acc[1] = (f32x16)(0.f);

    #pragma unroll 4
    for (int kc = 0; kc < 16; ++kc) {          // K chunks of 16
        short8 a0 = *(const short8*)(wbf + (kc*10 + w*2    )*512 + lane*8);
        short8 a1 = *(const short8*)(wbf + (kc*10 + w*2 + 1)*512 + lane*8);
        float xv[8];
        #pragma unroll
        for (int j = 0; j < 8; ++j)
            xv[j] = xt[kc*512 + (h*8 + j)*32 + l31];
        union { uint32_t d[4]; short8 s8; } bf;
        #pragma unroll
        for (int j2 = 0; j2 < 4; ++j2) bf.d[j2] = pktr(xv[2*j2], xv[2*j2+1]);
        acc[0] = __builtin_amdgcn_mfma_f32_32x32x16_bf16(a0, bf.s8, acc[0], 0, 0, 0);
        acc[1] = __builtin_amdgcn_mfma_f32_32x32x16_bf16(a1, bf.s8, acc[1], 0, 0, 0);
    }

    // epilogue: per mi subtile, transpose in LDS, store contiguous frags
    #pragma unroll
    for (int mi = 0; mi < 2; ++mi) {
        int rowb = w*64 + mi*32;
        bool isQK = (rowb < 64);
        #pragma unroll
        for (int r = 0; r < 16; ++r) {
            int roff = (r & 3) + 8*(r >> 2) + 4*h;
            ushort bv = f2bf(acc[mi][r] + ball[rowb + roff]);
            int ad = isQK ? (l31*40 + roff) : (roff*40 + l31);
            tr[w][ad] = bv;
        }
        __syncthreads();
        #pragma unroll
        for (int f = 0; f < 2; ++f) {
            us8 frag = *(const us8*)(&tr[w][l31*40 + f*16 + h*8]);
            if (isQK) {
                ushort* dstb = (rowb == 0) ? qg : ktg;
                size_t ad = ((size_t)((b*128 + nt)*2 + f) << 9) + lane*8;
                *(us8*)(dstb + ad) = frag;
            } else {
                int cblk = (rowb - 64) >> 5;
                int mb = nt*2 + f;
                size_t ad = ((size_t)((b*8 + cblk)*256 + mb) << 9) + lane*8;
                *(us8*)(vg + ad) = frag;
            }
        }
        __syncthreads();
    }
}

// ---------------- kernel 3: flash attention, FULL keys per block ------------
// R9: eliminated the ms-split (and with it pacc/lpart/k_comb entirely).
// grid = 512 blocks x 128 thr (2 waves): qp=blk&63 (64-q stripe), cs=bit6,
// b=bits[7:8]. Each wave: 32q x 128c over ALL 4096 keys (128 iters x 32).
// LDS exactly 20KB (V 8 frags + Kt 2, dbuf) -> 8 blocks/CU;
// __launch_bounds__(128,4): k = 4*4/(128/64) = 8 blocks/CU, 16 waves/CU
// = 4 waves/SIMD -- same occupancy as the 8-wave version, but barrier
// granularity 2 waves and 8 independent blocks/CU for cross-block overlap.
// Everything block-local: full l-sum per wave, direct gamma/l + x + out
// epilogue. No atomics/fences (R6/R7 failure modes structurally absent).
// Inner 32-key body identical math to the verified R1 kb-block.
__global__ __launch_bounds__(128, 4) void k_attn(
    const ushort* __restrict__ qg, const ushort* __restrict__ ktg,
    const ushort* __restrict__ vg,
    const float* __restrict__ x, const float* __restrict__ gamma_p,
    float* __restrict__ out)
{
    __shared__ ushort v_lds[2][8*512];    // 8 V frags [cfr*2 + mf] = 16KB
    __shared__ ushort kt_lds[2][2*512];   // 2 Kt frags [ks] = 4KB

    int blk = blockIdx.x;
    int qp = blk & 63;                 // 64-q stripe index
    int cs = (blk >> 6) & 1;
    int b  = blk >> 7;
    int t = threadIdx.x;
    int w = t >> 6, lane = t & 63;
    int l31 = lane & 31, h = lane >> 5;

    // Q fragments: wave w owns q-tile qp*2 + w
    short8 qf[2];
    #pragma unroll
    for (int ks = 0; ks < 2; ++ks)
        qf[ks] = *(const short8*)(qg
            + ((size_t)((b*128 + qp*2 + w)*2 + ks) << 9) + lane*8);

    f32x16 acc[4];
    #pragma unroll
    for (int j = 0; j < 4; ++j) acc[j] = (f32x16)(0.f);
    f32x2 lacc0 = {0.f, 0.f};
    f32x2 lacc1 = {0.f, 0.f};

    // staging per 32-key tile `kt`: V 8 frags (4/wave) + Kt 2 frags (1/wave)
    #define STAGE(bi, kti)                                                          \
    {                                                                               \
        _Pragma("unroll")                                                           \
        for (int ff = 0; ff < 4; ++ff) {                                            \
            int f = w*4 + ff;                                                       \
            int cfr = f >> 1, mf = f & 1;                                           \
            const ushort* src = vg + ((size_t)((b*8 + cs*4 + cfr)*256               \
                                 + (kti)*2 + mf) << 9) + lane*8;                    \
            __builtin_amdgcn_global_load_lds(                                       \
                (const __attribute__((address_space(1))) uint32_t*)src,             \
                (__attribute__((address_space(3))) uint32_t*)&v_lds[bi][f*512],     \
                16, 0, 0);                                                          \
        }                                                                           \
        {                                                                           \
            const ushort* src = ktg + ((size_t)((b*128 + (kti))*2 + w) << 9)        \
                                 + lane*8;                                          \
            __builtin_amdgcn_global_load_lds(                                       \
                (const __attribute__((address_space(1))) uint32_t*)src,             \
                (__attribute__((address_space(3))) uint32_t*)&kt_lds[bi][w*512],    \
                16, 0, 0);                                                          \
        }                                                                           \
    }

    #define PMERGE(uu, lo8, hi8)                                                    \
    {                                                                               \
        union { uint32_t d[4]; short8 s8; } fe_, fo_;                               \
        auto r02 = __builtin_amdgcn_permlane32_swap((int)uu[0], (int)uu[2], false, false); \
        auto r13 = __builtin_amdgcn_permlane32_swap((int)uu[1], (int)uu[3], false, false); \
        auto r46 = __builtin_amdgcn_permlane32_swap((int)uu[4], (int)uu[6], false, false); \
        auto r57 = __builtin_amdgcn_permlane32_swap((int)uu[5], (int)uu[7], false, false); \
        fe_.d[0] = (uint32_t)r02[0];  fe_.d[1] = (uint32_t)r13[0];                  \
        fe_.d[2] = (uint32_t)r02[1];  fe_.d[3] = (uint32_t)r13[1];                  \
        fo_.d[0] = (uint32_t)r46[0];  fo_.d[1] = (uint32_t)r57[0];                  \
        fo_.d[2] = (uint32_t)r46[1];  fo_.d[3] = (uint32_t)r57[1];                  \
        lo8 = fe_.s8;  hi8 = fo_.s8;                                               \
    }

    STAGE(0, 0)
    __syncthreads();

    int buf = 0;
    for (int it = 0; it < 128; ++it) {
        if (it + 1 < 128) STAGE(buf ^ 1, it + 1)

        // ---- QK (prio-boosted) ----
        short8 kt0 = *(const short8*)(&kt_lds[buf][0*512 + lane*8]);
        short8 kt1 = *(const short8*)(&kt_lds[buf][1*512 + lane*8]);
        f32x16 s = (f32x16)(0.f);
        __builtin_amdgcn_s_setprio(1);
        s = __builtin_amdgcn_mfma_f32_32x32x16_bf16(kt0, qf[0], s, 0, 0, 0);
        s = __builtin_amdgcn_mfma_f32_32x32x16_bf16(kt1, qf[1], s, 0, 0, 0);
        __builtin_amdgcn_s_setprio(0);

        // ---- softmax: exp2 + pack + permlane ----
        uint32_t u[8];
        #pragma unroll
        for (int i = 0; i < 8; ++i) {
            f32x2 e01;
            u[i] = fexp2_pk(s[2*i], s[2*i+1], e01);
            if (i & 1) lacc1 += e01; else lacc0 += e01;
        }
        short8 pf0, pf1;
        PMERGE(u, pf0, pf1)

        // ---- PV (prio-boosted) ----
        __builtin_amdgcn_s_setprio(1);
        #pragma unroll
        for (int msub = 0; msub < 2; ++msub) {
            short8 pfm = msub ? pf1 : pf0;
            #pragma unroll
            for (int cfr = 0; cfr < 4; ++cfr) {
                short8 vf = *(const short8*)(&v_lds[buf][(cfr*2 + msub)*512 + lane*8]);
                acc[cfr] = __builtin_amdgcn_mfma_f32_32x32x16_bf16(vf, pfm, acc[cfr], 0, 0, 0);
            }
        }
        __builtin_amdgcn_s_setprio(0);

        __syncthreads();
        buf ^= 1;
    }

    // ---- epilogue: full l per wave -> gamma/l, add x, write out -----------
    f32x2 lacc = lacc0 + lacc1;
    float lsum = lacc.x + lacc.y;
    {
        union { float f; int i; } cv; cv.f = lsum;
        cv.i = __shfl_xor(cv.i, 32);
        lsum += cv.f;
    }
    float rl = gamma_p[0] / lsum;

    int q = qp*64 + w*32 + l31;
    const float* xb = x + (size_t)b*C_*HW_ + q;
    float* ob = out + (size_t)b*C_*HW_ + q;
    #pragma unroll
    for (int cfr = 0; cfr < 4; ++cfr) {
        #pragma unroll
        for (int i = 0; i < 16; ++i) {
            int c = cs*128 + cfr*32 + (i & 3) + 8*(i >> 2) + 4*h;
            size_t off = (size_t)c*HW_;
            ob[off] = acc[cfr][i]*rl + xb[off];
        }
    }
    #undef STAGE
    #undef PMERGE
}

extern "C" void kernel_launch(void* const* d_in, const int* in_sizes, int n_in,
                              void* d_out, int out_size, void* d_ws, size_t ws_size,
                              hipStream_t stream)
{
    const float* x      = (const float*)d_in[0];
    const float* conv_w = (const float*)d_in[1];
    const float* conv_b = (const float*)d_in[2];
    const float* q_w    = (const float*)d_in[3];
    const float* q_b    = (const float*)d_in[4];
    const float* k_w    = (const float*)d_in[5];
    const float* k_b    = (const float*)d_in[6];
    const float* v_w    = (const float*)d_in[7];
    const float* v_b    = (const float*)d_in[8];
    const float* gamma  = (const float*)d_in[9];
    float* out = (float*)d_out;

    char* ws = (char*)d_ws;
    ushort* wbf   = (ushort*)(ws + WT_OFF);
    float*  ball  = (float*)(ws + BALL_OFF);
    ushort* qg    = (ushort*)(ws + Q_OFF);
    ushort* ktg   = (ushort*)(ws + KT_OFF);
    ushort* vg    = (ushort*)(ws + V_OFF);

    k_setup<<<ROWS_, 256, 0, stream>>>(conv_w, conv_b, q_w, q_b, k_w, k_b,
                                       v_w, v_b, wbf, ball);
    k_qkv<<<B_*128, 320, 0, stream>>>(x, wbf, ball, qg, ktg, vg);
    k_attn<<<512, 128, 0, stream>>>(qg, ktg, vg, x, gamma, out);
}

// Round 11
// 153.139 us; speedup vs baseline: 1.3603x; 1.3603x over previous
//
#include <hip/hip_runtime.h>
#include <hip/hip_bf16.h>
#include <stdint.h>

#define B_   4
#define C_   256
#define C8_  32
#define HW_  4096
#define ROWS_ 320   // 32 Q + 32 K + 256 V composite rows
#define MS_  4      // m-split factor
#define L2E  1.4426950408889634f

typedef __attribute__((ext_vector_type(8)))  short  short8;
typedef __attribute__((ext_vector_type(8)))  ushort us8;
typedef __attribute__((ext_vector_type(2)))  float  f32x2;
typedef __attribute__((ext_vector_type(16))) float  f32x16;

// ---- workspace layout (bytes) ----
#define WT_OFF    0
#define BALL_OFF  (256*320*4)
#define Q_OFF     (BALL_OFF + 1280)
#define KT_OFF    (Q_OFF  + B_*HW_*C8_*2)
#define V_OFF     (KT_OFF + B_*HW_*C8_*2)
#define PACC_OFF  (V_OFF  + B_*C_*HW_*2)
#define LPART_OFF (PACC_OFF + (size_t)MS_*B_*C_*HW_*2)

__device__ __forceinline__ ushort f2bf(float f) {
    union { float f; uint32_t u; } v; v.f = f;
    uint32_t u = v.u;
    uint32_t r = u + 0x7fffu + ((u >> 16) & 1u);  // RNE
    return (ushort)(r >> 16);
}
__device__ __forceinline__ uint32_t pktr(float lo, float hi) {
    union { float f; uint32_t u; } a, b; a.f = lo; b.f = hi;
    return __builtin_amdgcn_perm(b.u, a.u, 0x07060302u);  // 1-instr trunc pack
}
// Packed Schraudolph exp2 on a pair: v_pk_fma + v_pk_max + 2 cvt + 1 perm.
__device__ __forceinline__ uint32_t fexp2_pk(float s0, float s1, f32x2& e01) {
    f32x2 s = {s0, s1};
    f32x2 y = __builtin_elementwise_fma(s, (f32x2)(8388608.0f),
                                        (f32x2)(1064992506.0f)); // (127-0.043)*2^23
    y = __builtin_elementwise_max(y, (f32x2)(0.0f));
    union { int i; float f; } c0, c1;
    c0.i = (int)y.x;  c1.i = (int)y.y;
    e01.x = c0.f;  e01.y = c1.f;
    return __builtin_amdgcn_perm((uint32_t)c1.i, (uint32_t)c0.i, 0x07060302u);
}

// ---------------- kernel 1: fold conv into weights (bf16, A-frag-major) ----
__global__ __launch_bounds__(256) void k_setup(
    const float* __restrict__ conv_w, const float* __restrict__ conv_b,
    const float* __restrict__ q_w, const float* __restrict__ q_b,
    const float* __restrict__ k_w, const float* __restrict__ k_b,
    const float* __restrict__ v_w, const float* __restrict__ v_b,
    ushort* __restrict__ wbf, float* __restrict__ ball)
{
    int r = blockIdx.x;        // 0..319 composite row
    int c = threadIdx.x;       // 0..255 input channel (k)
    const float* wrow;
    float bias;
    if (r < 32)       { wrow = q_w + r*32;      bias = q_b[r];      }
    else if (r < 64)  { wrow = k_w + (r-32)*32; bias = k_b[r-32];   }
    else              { wrow = v_w + (r-64)*32; bias = v_b[r-64];   }
    float acc = 0.f;
    #pragma unroll
    for (int d = 0; d < 32; ++d) acc += wrow[d] * conv_w[d*C_ + c];
    float scale = (r < 32) ? L2E : 1.0f;       // fold log2(e) into Q
    int lanew = (r & 31) + 32*((c >> 3) & 1);
    int fidx  = (c >> 4)*10 + (r >> 5);        // [kc][rowblk]
    wbf[fidx*512 + lanew*8 + (c & 7)] = f2bf(acc * scale);
    if (c == 0) {
        float bb = bias;
        #pragma unroll
        for (int d = 0; d < 32; ++d) bb += wrow[d] * conv_b[d];
        ball[r] = bb * scale;
    }
}

// ---------------- kernel 2: Q/Kt/V projection via MFMA + LDS transpose -----
// grid = B*128, 320 thr (5 waves = 320 rows x 32 n). R8-measured version:
// bulk x-tile stage via global_load_lds (was 5x redundant strided loads).
__global__ __launch_bounds__(320) void k_qkv(
    const float* __restrict__ x, const ushort* __restrict__ wbf,
    const float* __restrict__ ball,
    ushort* __restrict__ qg, ushort* __restrict__ ktg, ushort* __restrict__ vg)
{
    __shared__ float  xt[256*32];     // 32KB staged x tile [c(256)][n(32)]
    __shared__ ushort tr[5][32*40];   // per-wave 32x32 transpose tile

    int blk = blockIdx.x;
    int b  = blk >> 7;
    int nt = blk & 127;                // n-tile index (32 cols)
    int n0 = nt * 32;
    int t = threadIdx.x;
    int w = t >> 6, lane = t & 63;
    int l31 = lane & 31, h = lane >> 5;

    const float* xsrc = x + (size_t)b*C_*HW_ + n0;
    if (w < 4) {
        #pragma unroll
        for (int i = 0; i < 8; ++i) {
            int chunk = w*8 + i;
            const float* src = xsrc + (size_t)(chunk*8 + (lane >> 3))*HW_
                               + (lane & 7)*4;
            __builtin_amdgcn_global_load_lds(
                (const __attribute__((address_space(1))) uint32_t*)src,
                (__attribute__((address_space(3))) uint32_t*)&xt[chunk*256],
                16, 0, 0);
        }
    }
    __syncthreads();

    f32x16 acc[2];
    acc[0] = (f32x16)(0.f);
    acc[1] = (f32x16)(0.f);

    #pragma unroll 4
    for (int kc = 0; kc < 16; ++kc) {          // K chunks of 16
        short8 a0 = *(const short8*)(wbf + (kc*10 + w*2    )*512 + lane*8);
        short8 a1 = *(const short8*)(wbf + (kc*10 + w*2 + 1)*512 + lane*8);
        float xv[8];
        #pragma unroll
        for (int j = 0; j < 8; ++j)
            xv[j] = xt[kc*512 + (h*8 + j)*32 + l31];
        union { uint32_t d[4]; short8 s8; } bf;
        #pragma unroll
        for (int j2 = 0; j2 < 4; ++j2) bf.d[j2] = pktr(xv[2*j2], xv[2*j2+1]);
        acc[0] = __builtin_amdgcn_mfma_f32_32x32x16_bf16(a0, bf.s8, acc[0], 0, 0, 0);
        acc[1] = __builtin_amdgcn_mfma_f32_32x32x16_bf16(a1, bf.s8, acc[1], 0, 0, 0);
    }

    // epilogue: per mi subtile, transpose in LDS, store contiguous frags
    #pragma unroll
    for (int mi = 0; mi < 2; ++mi) {
        int rowb = w*64 + mi*32;
        bool isQK = (rowb < 64);
        #pragma unroll
        for (int r = 0; r < 16; ++r) {
            int roff = (r & 3) + 8*(r >> 2) + 4*h;
            ushort bv = f2bf(acc[mi][r] + ball[rowb + roff]);
            int ad = isQK ? (l31*40 + roff) : (roff*40 + l31);
            tr[w][ad] = bv;
        }
        __syncthreads();
        #pragma unroll
        for (int f = 0; f < 2; ++f) {
            us8 frag = *(const us8*)(&tr[w][l31*40 + f*16 + h*8]);
            if (isQK) {
                ushort* dstb = (rowb == 0) ? qg : ktg;
                size_t ad = ((size_t)((b*128 + nt)*2 + f) << 9) + lane*8;
                *(us8*)(dstb + ad) = frag;
            } else {
                int cblk = (rowb - 64) >> 5;
                int mb = nt*2 + f;
                size_t ad = ((size_t)((b*8 + cblk)*256 + mb) << 9) + lane*8;
                *(us8*)(vg + ad) = frag;
            }
        }
        __syncthreads();
    }
}

// ---------------- kernel 3: flash attention, m-split partials ----------------
// R10: same 4096-wave decomposition as R8 (R9 lesson: the ms-split IS the
// parallelism; 2-wave/512-block collapsed to 1 wave/SIMD), but blocks split
// 8 waves -> 4 waves: grid 1024 x 256 thr. LDS 40960 x 4 = exactly 160KiB
// -> 4 blocks/CU, 16 waves/CU (same occupancy), with 3 (vs 1) independent
// blocks to cover each block's barrier drain and half the straggler width
// per __syncthreads. Index map keeps pacc/lpart layout BIT-IDENTICAL to R8:
// qbold = qb5>>1, wold = (qb5&1)*4 + w. Per-wave work/math unchanged (R1
// body: permlane T12, setprio T5, 2-stage pipeline).
__global__ __launch_bounds__(256, 4) void k_attn(
    const ushort* __restrict__ qg, const ushort* __restrict__ ktg,
    const ushort* __restrict__ vg,
    ushort* __restrict__ pacc, float* __restrict__ lpart)
{
    __shared__ ushort v_lds[2][16*512];   // 16 V frags [cfr*4 + mf] = 32KB
    __shared__ ushort kt_lds[2][4*512];   // 4 Kt frags [kb*2 + ks]  = 8KB

    int blk = blockIdx.x;
    int ms  = blk & 3;
    int cs  = (blk >> 2) & 1;
    int qb5 = (blk >> 3) & 31;         // 128-q stripe
    int b   = blk >> 8;
    int t = threadIdx.x;
    int w = t >> 6, lane = t & 63;     // w in 0..3
    int l31 = lane & 31, h = lane >> 5;
    int mbase = ms*1024;

    // Q fragments: wave w owns q-tile qb5*4 + w
    short8 qf[2];
    #pragma unroll
    for (int ks = 0; ks < 2; ++ks)
        qf[ks] = *(const short8*)(qg
            + ((size_t)((b*128 + qb5*4 + w)*2 + ks) << 9) + lane*8);

    f32x16 acc[4];
    #pragma unroll
    for (int j = 0; j < 4; ++j) acc[j] = (f32x16)(0.f);
    f32x2 lacc0 = {0.f, 0.f};
    f32x2 lacc1 = {0.f, 0.f};

    // staging: V 16 frags -> 4/wave ; Kt 4 frags -> 1/wave
    #define STAGE(buf, m0)                                                          \
    {                                                                               \
        _Pragma("unroll")                                                           \
        for (int ff = 0; ff < 4; ++ff) {                                            \
            int f = w*4 + ff;                                                       \
            int cfr = f >> 2, mf = f & 3;                                           \
            const ushort* src = vg + ((size_t)((b*8 + cs*4 + cfr)*256               \
                                 + ((m0) >> 4) + mf) << 9) + lane*8;                \
            __builtin_amdgcn_global_load_lds(                                       \
                (const __attribute__((address_space(1))) uint32_t*)src,             \
                (__attribute__((address_space(3))) uint32_t*)&v_lds[buf][f*512],    \
                16, 0, 0);                                                          \
        }                                                                           \
        {                                                                           \
            const ushort* src = ktg + ((size_t)((b*128 + ((m0) >> 5) + (w >> 1))*2  \
                                 + (w & 1)) << 9) + lane*8;                         \
            __builtin_amdgcn_global_load_lds(                                       \
                (const __attribute__((address_space(1))) uint32_t*)src,             \
                (__attribute__((address_space(3))) uint32_t*)&kt_lds[buf][w*512],   \
                16, 0, 0);                                                          \
        }                                                                           \
    }

    #define PMERGE(uu, lo8, hi8)                                                    \
    {                                                                               \
        union { uint32_t d[4]; short8 s8; } fe_, fo_;                               \
        auto r02 = __builtin_amdgcn_permlane32_swap((int)uu[0], (int)uu[2], false, false); \
        auto r13 = __builtin_amdgcn_permlane32_swap((int)uu[1], (int)uu[3], false, false); \
        auto r46 = __builtin_amdgcn_permlane32_swap((int)uu[4], (int)uu[6], false, false); \
        auto r57 = __builtin_amdgcn_permlane32_swap((int)uu[5], (int)uu[7], false, false); \
        fe_.d[0] = (uint32_t)r02[0];  fe_.d[1] = (uint32_t)r13[0];                  \
        fe_.d[2] = (uint32_t)r02[1];  fe_.d[3] = (uint32_t)r13[1];                  \
        fo_.d[0] = (uint32_t)r46[0];  fo_.d[1] = (uint32_t)r57[0];                  \
        fo_.d[2] = (uint32_t)r46[1];  fo_.d[3] = (uint32_t)r57[1];                  \
        lo8 = fe_.s8;  hi8 = fo_.s8;                                               \
    }

    STAGE(0, mbase)
    __syncthreads();

    int buf = 0;
    for (int it = 0; it < 16; ++it) {
        if (it + 1 < 16) STAGE(buf ^ 1, mbase + (it+1)*64)

        // ---- QK kb=0 (head cluster, prio-boosted) ----
        short8 kt0a = *(const short8*)(&kt_lds[buf][0*512 + lane*8]);
        short8 kt1a = *(const short8*)(&kt_lds[buf][1*512 + lane*8]);
        f32x16 s_a = (f32x16)(0.f);
        __builtin_amdgcn_s_setprio(1);
        s_a = __builtin_amdgcn_mfma_f32_32x32x16_bf16(kt0a, qf[0], s_a, 0, 0, 0);
        s_a = __builtin_amdgcn_mfma_f32_32x32x16_bf16(kt1a, qf[1], s_a, 0, 0, 0);
        __builtin_amdgcn_s_setprio(0);

        // ---- SM_a: exp2 + pack + permlane ----
        uint32_t ua[8];
        #pragma unroll
        for (int i = 0; i < 8; ++i) {
            f32x2 e01;
            ua[i] = fexp2_pk(s_a[2*i], s_a[2*i+1], e01);
            if (i & 1) lacc1 += e01; else lacc0 += e01;
        }
        short8 pfa0, pfa1;
        PMERGE(ua, pfa0, pfa1)

        // ---- QK kb=1 (issued early; executes under SM_a tail / PV_a head) ----
        short8 kt0b = *(const short8*)(&kt_lds[buf][2*512 + lane*8]);
        short8 kt1b = *(const short8*)(&kt_lds[buf][3*512 + lane*8]);
        f32x16 s_b = (f32x16)(0.f);
        s_b = __builtin_amdgcn_mfma_f32_32x32x16_bf16(kt0b, qf[0], s_b, 0, 0, 0);
        s_b = __builtin_amdgcn_mfma_f32_32x32x16_bf16(kt1b, qf[1], s_b, 0, 0, 0);

        // ---- fence-free region: SM_b VALU interleaves with PV_a MFMA ----
        uint32_t ub[8];
        #pragma unroll
        for (int i = 0; i < 8; ++i) {
            f32x2 e01;
            ub[i] = fexp2_pk(s_b[2*i], s_b[2*i+1], e01);
            if (i & 1) lacc1 += e01; else lacc0 += e01;
        }
        #pragma unroll
        for (int msub = 0; msub < 2; ++msub) {     // PV_a: keys [0,32)
            short8 pfm = msub ? pfa1 : pfa0;
            int ks16 = msub;
            #pragma unroll
            for (int cfr = 0; cfr < 4; ++cfr) {
                short8 vf = *(const short8*)(&v_lds[buf][(cfr*4 + ks16)*512 + lane*8]);
                acc[cfr] = __builtin_amdgcn_mfma_f32_32x32x16_bf16(vf, pfm, acc[cfr], 0, 0, 0);
            }
        }
        short8 pfb0, pfb1;
        PMERGE(ub, pfb0, pfb1)

        // ---- PV_b (tail cluster, prio-boosted) ----
        __builtin_amdgcn_s_setprio(1);
        #pragma unroll
        for (int msub = 0; msub < 2; ++msub) {     // keys [32,64)
            short8 pfm = msub ? pfb1 : pfb0;
            int ks16 = 2 + msub;
            #pragma unroll
            for (int cfr = 0; cfr < 4; ++cfr) {
                short8 vf = *(const short8*)(&v_lds[buf][(cfr*4 + ks16)*512 + lane*8]);
                acc[cfr] = __builtin_amdgcn_mfma_f32_32x32x16_bf16(vf, pfm, acc[cfr], 0, 0, 0);
            }
        }
        __builtin_amdgcn_s_setprio(0);

        __syncthreads();
        buf ^= 1;
    }

    // finalize l: horizontal + other lane-half's key contributions
    f32x2 lacc = lacc0 + lacc1;
    float lsum = lacc.x + lacc.y;
    {
        union { float f; int i; } cv; cv.f = lsum;
        cv.i = __shfl_xor(cv.i, 32);
        lsum += cv.f;
    }
    int q = qb5*128 + w*32 + l31;
    if (cs == 0 && h == 0)
        lpart[(size_t)(ms*B_ + b)*HW_ + q] = lsum;

    // pacc: bit-identical layout to R8 (qbold = qb5>>1, wold = (qb5&1)*4+w)
    int qbold = qb5 >> 1;
    int wold  = (qb5 & 1)*4 + w;
    int blkl = ((ms*B_ + b)*16 + qbold)*2 + cs;
    #pragma unroll
    for (int cfr = 0; cfr < 4; ++cfr) {
        union { uint32_t d[8]; us8 hlf[2]; } pk;
        #pragma unroll
        for (int i = 0; i < 8; ++i)
            pk.d[i] = pktr(acc[cfr][2*i], acc[cfr][2*i+1]);
        ushort* dst = pacc + ((size_t)(blkl*32 + wold*4 + cfr) << 10);
        *(us8*)(dst + lane*8)       = pk.hlf[0];
        *(us8*)(dst + 512 + lane*8) = pk.hlf[1];
    }
    #undef STAGE
    #undef PMERGE
}

// ---------------- kernel 4: combine via LDS transpose + epilogue ----------
// grid = 1024 blocks (b,qb,cs,w), 256 thr. Byte-identical to R8.
__global__ __launch_bounds__(256) void k_comb(
    const ushort* __restrict__ pacc, const float* __restrict__ lpart,
    const float* __restrict__ x, const float* __restrict__ gamma_p,
    float* __restrict__ out)
{
    __shared__ float lds_acc[128*36];   // 18.4 KB

    int blk = blockIdx.x;
    int w  = blk & 7;
    int cs = (blk >> 3) & 1;
    int qb = (blk >> 4) & 15;
    int b  = blk >> 8;
    int t = threadIdx.x;

    int l31 = t & 31;
    int h   = (t >> 5) & 1;
    int cfr = (t >> 6) & 3;
    int q = qb*256 + w*32 + l31;
    int lanef = h*32 + l31;

    float sum[16];
    #pragma unroll
    for (int k = 0; k < 16; ++k) sum[k] = 0.f;
    float lt = 0.f;

    #pragma unroll
    for (int ms = 0; ms < MS_; ++ms) {
        int blkl = ((ms*B_ + b)*16 + qb)*2 + cs;
        const ushort* pp = pacc + ((size_t)(blkl*32 + w*4 + cfr) << 10) + lanef*8;
        us8 a0 = *(const us8*)pp;
        us8 a1 = *(const us8*)(pp + 512);
        #pragma unroll
        for (int k = 0; k < 8; ++k) {
            union { uint32_t u; float f; } cv;
            cv.u = ((uint32_t)a0[k]) << 16;  sum[k]   += cv.f;
            cv.u = ((uint32_t)a1[k]) << 16;  sum[k+8] += cv.f;
        }
        lt += lpart[(size_t)(ms*B_ + b)*HW_ + q];
    }

    float rl = gamma_p[0] / lt;
    #pragma unroll
    for (int k = 0; k < 16; ++k) {
        int c = cfr*32 + (k & 3) + 8*(k >> 2) + 4*h;
        lds_acc[c*36 + l31] = sum[k]*rl;
    }
    __syncthreads();

    // phase 2: 1024 float4 slots [c(128)][qg(8)]; thread does 4 slots
    const float* xb = x + ((size_t)(b*C_ + cs*128))*HW_ + qb*256 + w*32;
    float* ob = out + ((size_t)(b*C_ + cs*128))*HW_ + qb*256 + w*32;
    #pragma unroll
    for (int i = 0; i < 4; ++i) {
        int s = t + i*256;
        int c = s >> 3, qg = s & 7;
        float4 a = *(const float4*)(&lds_acc[c*36 + qg*4]);
        size_t off = (size_t)c*HW_ + qg*4;
        float4 xv = *(const float4*)(xb + off);
        a.x += xv.x; a.y += xv.y; a.z += xv.z; a.w += xv.w;
        *(float4*)(ob + off) = a;
    }
}

extern "C" void kernel_launch(void* const* d_in, const int* in_sizes, int n_in,
                              void* d_out, int out_size, void* d_ws, size_t ws_size,
                              hipStream_t stream)
{
    const float* x      = (const float*)d_in[0];
    const float* conv_w = (const float*)d_in[1];
    const float* conv_b = (const float*)d_in[2];
    const float* q_w    = (const float*)d_in[3];
    const float* q_b    = (const float*)d_in[4];
    const float* k_w    = (const float*)d_in[5];
    const float* k_b    = (const float*)d_in[6];
    const float* v_w    = (const float*)d_in[7];
    const float* v_b    = (const float*)d_in[8];
    const float* gamma  = (const float*)d_in[9];
    float* out = (float*)d_out;

    char* ws = (char*)d_ws;
    ushort* wbf   = (ushort*)(ws + WT_OFF);
    float*  ball  = (float*)(ws + BALL_OFF);
    ushort* qg    = (ushort*)(ws + Q_OFF);
    ushort* ktg   = (ushort*)(ws + KT_OFF);
    ushort* vg    = (ushort*)(ws + V_OFF);
    ushort* pacc  = (ushort*)(ws + PACC_OFF);
    float*  lpart = (float*)(ws + LPART_OFF);

    k_setup<<<ROWS_, 256, 0, stream>>>(conv_w, conv_b, q_w, q_b, k_w, k_b,
                                       v_w, v_b, wbf, ball);
    k_qkv<<<B_*128, 320, 0, stream>>>(x, wbf, ball, qg, ktg, vg);
    k_attn<<<1024, 256, 0, stream>>>(qg, ktg, vg, pacc, lpart);
    k_comb<<<1024, 256, 0, stream>>>(pacc, lpart, x, gamma, out);
}

// Round 13
// 149.239 us; speedup vs baseline: 1.3959x; 1.0261x over previous
//
#include <hip/hip_runtime.h>
#include <hip/hip_bf16.h>
#include <stdint.h>

#define B_   4
#define C_   256
#define C8_  32
#define HW_  4096
#define ROWS_ 320   // 32 Q + 32 K + 256 V composite rows
#define MS_  4      // m-split factor
#define L2E  1.4426950408889634f

typedef __attribute__((ext_vector_type(8)))  short  short8;
typedef __attribute__((ext_vector_type(8)))  ushort us8;
typedef __attribute__((ext_vector_type(2)))  float  f32x2;
typedef __attribute__((ext_vector_type(16))) float  f32x16;

// ---- workspace layout (bytes) ----
#define WT_OFF    0
#define BALL_OFF  (256*320*4)
#define Q_OFF     (BALL_OFF + 1280)
#define KT_OFF    (Q_OFF  + B_*HW_*C8_*2)
#define V_OFF     (KT_OFF + B_*HW_*C8_*2)
#define PACC_OFF  (V_OFF  + B_*C_*HW_*2)
#define LPART_OFF (PACC_OFF + (size_t)MS_*B_*C_*HW_*2)

__device__ __forceinline__ ushort f2bf(float f) {
    union { float f; uint32_t u; } v; v.f = f;
    uint32_t u = v.u;
    uint32_t r = u + 0x7fffu + ((u >> 16) & 1u);  // RNE
    return (ushort)(r >> 16);
}
__device__ __forceinline__ uint32_t pktr(float lo, float hi) {
    union { float f; uint32_t u; } a, b; a.f = lo; b.f = hi;
    return __builtin_amdgcn_perm(b.u, a.u, 0x07060302u);  // 1-instr trunc pack
}
// RNE pack of two f32 -> packed bf16 pair, single VALU op (no builtin; m240).
__device__ __forceinline__ uint32_t pkrne(float lo, float hi) {
    uint32_t r;
    asm("v_cvt_pk_bf16_f32 %0, %1, %2" : "=v"(r) : "v"(lo), "v"(hi));
    return r;
}
// R12: exp2 on the TRANSCENDENTAL pipe, hazard-safe. R11's raw
// asm("v_exp_f32") was an opaque box: the hazard recognizer could not see
// the TRANS op inside, so no wait-state was inserted before the dependent
// cvt_pk -> stale-register garbage (absmax 98). The builtin goes through
// llvm.amdgcn.exp2.f32 and gets proper hazard scheduling; fallback keeps
// an explicit s_nop 1 wait-state inside the asm.
__device__ __forceinline__ float exp2_hw(float s) {
#if __has_builtin(__builtin_amdgcn_exp2f)
    return __builtin_amdgcn_exp2f(s);
#else
    float e;
    asm volatile("v_exp_f32 %0, %1\n\ts_nop 1" : "=v"(e) : "v"(s));
    return e;
#endif
}
__device__ __forceinline__ uint32_t fexp2_pk(float s0, float s1, f32x2& e01) {
    float e0 = exp2_hw(s0);
    float e1 = exp2_hw(s1);
    e01.x = e0;  e01.y = e1;
    return pkrne(e0, e1);
}

// ---------------- kernel 1: fold conv into weights (bf16, A-frag-major) ----
__global__ __launch_bounds__(256) void k_setup(
    const float* __restrict__ conv_w, const float* __restrict__ conv_b,
    const float* __restrict__ q_w, const float* __restrict__ q_b,
    const float* __restrict__ k_w, const float* __restrict__ k_b,
    const float* __restrict__ v_w, const float* __restrict__ v_b,
    ushort* __restrict__ wbf, float* __restrict__ ball)
{
    int r = blockIdx.x;        // 0..319 composite row
    int c = threadIdx.x;       // 0..255 input channel (k)
    const float* wrow;
    float bias;
    if (r < 32)       { wrow = q_w + r*32;      bias = q_b[r];      }
    else if (r < 64)  { wrow = k_w + (r-32)*32; bias = k_b[r-32];   }
    else              { wrow = v_w + (r-64)*32; bias = v_b[r-64];   }
    float acc = 0.f;
    #pragma unroll
    for (int d = 0; d < 32; ++d) acc += wrow[d] * conv_w[d*C_ + c];
    float scale = (r < 32) ? L2E : 1.0f;       // fold log2(e) into Q
    int lanew = (r & 31) + 32*((c >> 3) & 1);
    int fidx  = (c >> 4)*10 + (r >> 5);        // [kc][rowblk]
    wbf[fidx*512 + lanew*8 + (c & 7)] = f2bf(acc * scale);
    if (c == 0) {
        float bb = bias;
        #pragma unroll
        for (int d = 0; d < 32; ++d) bb += wrow[d] * conv_b[d];
        ball[r] = bb * scale;
    }
}

// ---------------- kernel 2: Q/Kt/V projection via MFMA + LDS transpose -----
// grid = B*128, 320 thr (5 waves = 320 rows x 32 n). R8-measured version:
// bulk x-tile stage via global_load_lds (was 5x redundant strided loads).
__global__ __launch_bounds__(320) void k_qkv(
    const float* __restrict__ x, const ushort* __restrict__ wbf,
    const float* __restrict__ ball,
    ushort* __restrict__ qg, ushort* __restrict__ ktg, ushort* __restrict__ vg)
{
    __shared__ float  xt[256*32];     // 32KB staged x tile [c(256)][n(32)]
    __shared__ ushort tr[5][32*40];   // per-wave 32x32 transpose tile

    int blk = blockIdx.x;
    int b  = blk >> 7;
    int nt = blk & 127;                // n-tile index (32 cols)
    int n0 = nt * 32;
    int t = threadIdx.x;
    int w = t >> 6, lane = t & 63;
    int l31 = lane & 31, h = lane >> 5;

    const float* xsrc = x + (size_t)b*C_*HW_ + n0;
    if (w < 4) {
        #pragma unroll
        for (int i = 0; i < 8; ++i) {
            int chunk = w*8 + i;
            const float* src = xsrc + (size_t)(chunk*8 + (lane >> 3))*HW_
                               + (lane & 7)*4;
            __builtin_amdgcn_global_load_lds(
                (const __attribute__((address_space(1))) uint32_t*)src,
                (__attribute__((address_space(3))) uint32_t*)&xt[chunk*256],
                16, 0, 0);
        }
    }
    __syncthreads();

    f32x16 acc[2];
    acc[0] = (f32x16)(0.f);
    acc[1] = (f32x16)(0.f);

    #pragma unroll 4
    for (int kc = 0; kc < 16; ++kc) {          // K chunks of 16
        short8 a0 = *(const short8*)(wbf + (kc*10 + w*2    )*512 + lane*8);
        short8 a1 = *(const short8*)(wbf + (kc*10 + w*2 + 1)*512 + lane*8);
        float xv[8];
        #pragma unroll
        for (int j = 0; j < 8; ++j)
            xv[j] = xt[kc*512 + (h*8 + j)*32 + l31];
        union { uint32_t d[4]; short8 s8; } bf;
        #pragma unroll
        for (int j2 = 0; j2 < 4; ++j2) bf.d[j2] = pktr(xv[2*j2], xv[2*j2+1]);
        acc[0] = __builtin_amdgcn_mfma_f32_32x32x16_bf16(a0, bf.s8, acc[0], 0, 0, 0);
        acc[1] = __builtin_amdgcn_mfma_f32_32x32x16_bf16(a1, bf.s8, acc[1], 0, 0, 0);
    }

    // epilogue: per mi subtile, transpose in LDS, store contiguous frags
    #pragma unroll
    for (int mi = 0; mi < 2; ++mi) {
        int rowb = w*64 + mi*32;
        bool isQK = (rowb < 64);
        #pragma unroll
        for (int r = 0; r < 16; ++r) {
            int roff = (r & 3) + 8*(r >> 2) + 4*h;
            ushort bv = f2bf(acc[mi][r] + ball[rowb + roff]);
            int ad = isQK ? (l31*40 + roff) : (roff*40 + l31);
            tr[w][ad] = bv;
        }
        __syncthreads();
        #pragma unroll
        for (int f = 0; f < 2; ++f) {
            us8 frag = *(const us8*)(&tr[w][l31*40 + f*16 + h*8]);
            if (isQK) {
                ushort* dstb = (rowb == 0) ? qg : ktg;
                size_t ad = ((size_t)((b*128 + nt)*2 + f) << 9) + lane*8;
                *(us8*)(dstb + ad) = frag;
            } else {
                int cblk = (rowb - 64) >> 5;
                int mb = nt*2 + f;
                size_t ad = ((size_t)((b*8 + cblk)*256 + mb) << 9) + lane*8;
                *(us8*)(vg + ad) = frag;
            }
        }
        __syncthreads();
    }
}

// ---------------- kernel 3: flash attention, m-split partials ----------------
// grid = 512: ms=blk&3, cs=bit2, qb=bits[3:6], b=bits[7:8]. 512 thr = 8 waves;
// wave = 32q x 128c, acc 64 AGPR, 4 waves/SIMD (structural cap: 128 regs/wave).
// R1-measured best structure (150.2us total). R0: permlane32_swap (T12);
// setprio (T5). R1: 2-stage pipeline. R12: trans-pipe exp2 via builtin
// (R11's raw asm broke the TRANS hazard -- opaque to hazard recognizer).
// Structural variants all regressed: R3 vmcnt-dbuf null, R4 16-wave spill,
// R9 2-wave occupancy collapse, R10 4-wave -2us, R6/R7 fusion -170/-38us.
__global__ __launch_bounds__(512, 4) void k_attn(
    const ushort* __restrict__ qg, const ushort* __restrict__ ktg,
    const ushort* __restrict__ vg,
    ushort* __restrict__ pacc, float* __restrict__ lpart)
{
    __shared__ ushort v_lds[2][16*512];   // 16 V frags [cfr*4 + mf]
    __shared__ ushort kt_lds[2][4*512];   // 4 Kt frags [kb*2 + ks]

    int blk = blockIdx.x;
    int ms = blk & 3;
    int cs = (blk >> 2) & 1;
    int qb = (blk >> 3) & 15;
    int b  = blk >> 7;
    int t = threadIdx.x;
    int w = t >> 6, lane = t & 63;
    int l31 = lane & 31, h = lane >> 5;
    int mbase = ms*1024;

    short8 qf[2];
    #pragma unroll
    for (int ks = 0; ks < 2; ++ks)
        qf[ks] = *(const short8*)(qg
            + ((size_t)((b*128 + qb*8 + w)*2 + ks) << 9) + lane*8);

    f32x16 acc[4];
    #pragma unroll
    for (int j = 0; j < 4; ++j) acc[j] = (f32x16)(0.f);
    f32x2 lacc0 = {0.f, 0.f};
    f32x2 lacc1 = {0.f, 0.f};

    #define STAGE(buf, m0)                                                          \
    {                                                                               \
        _Pragma("unroll")                                                           \
        for (int ff = 0; ff < 2; ++ff) {                                            \
            int f = w*2 + ff;                                                       \
            int cfr = f >> 2, mf = f & 3;                                           \
            const ushort* src = vg + ((size_t)((b*8 + cs*4 + cfr)*256               \
                                 + ((m0) >> 4) + mf) << 9) + lane*8;                \
            __builtin_amdgcn_global_load_lds(                                       \
                (const __attribute__((address_space(1))) uint32_t*)src,             \
                (__attribute__((address_space(3))) uint32_t*)&v_lds[buf][f*512],    \
                16, 0, 0);                                                          \
        }                                                                           \
        if (w < 4) {                                                                \
            const ushort* src = ktg + ((size_t)((b*128 + ((m0) >> 5) + (w >> 1))*2  \
                                 + (w & 1)) << 9) + lane*8;                         \
            __builtin_amdgcn_global_load_lds(                                       \
                (const __attribute__((address_space(1))) uint32_t*)src,             \
                (__attribute__((address_space(3))) uint32_t*)&kt_lds[buf][w*512],   \
                16, 0, 0);                                                          \
        }                                                                           \
    }

    #define PMERGE(uu, lo8, hi8)                                                    \
    {                                                                               \
        union { uint32_t d[4]; short8 s8; } fe_, fo_;                               \
        auto r02 = __builtin_amdgcn_permlane32_swap((int)uu[0], (int)uu[2], false, false); \
        auto r13 = __builtin_amdgcn_permlane32_swap((int)uu[1], (int)uu[3], false, false); \
        auto r46 = __builtin_amdgcn_permlane32_swap((int)uu[4], (int)uu[6], false, false); \
        auto r57 = __builtin_amdgcn_permlane32_swap((int)uu[5], (int)uu[7], false, false); \
        fe_.d[0] = (uint32_t)r02[0];  fe_.d[1] = (uint32_t)r13[0];                  \
        fe_.d[2] = (uint32_t)r02[1];  fe_.d[3] = (uint32_t)r13[1];                  \
        fo_.d[0] = (uint32_t)r46[0];  fo_.d[1] = (uint32_t)r57[0];                  \
        fo_.d[2] = (uint32_t)r46[1];  fo_.d[3] = (uint32_t)r57[1];                  \
        lo8 = fe_.s8;  hi8 = fo_.s8;                                               \
    }

    STAGE(0, mbase)
    __syncthreads();

    int buf = 0;
    for (int it = 0; it < 16; ++it) {
        if (it + 1 < 16) STAGE(buf ^ 1, mbase + (it+1)*64)

        // ---- QK kb=0 (head cluster, prio-boosted) ----
        short8 kt0a = *(const short8*)(&kt_lds[buf][0*512 + lane*8]);
        short8 kt1a = *(const short8*)(&kt_lds[buf][1*512 + lane*8]);
        f32x16 s_a = (f32x16)(0.f);
        __builtin_amdgcn_s_setprio(1);
        s_a = __builtin_amdgcn_mfma_f32_32x32x16_bf16(kt0a, qf[0], s_a, 0, 0, 0);
        s_a = __builtin_amdgcn_mfma_f32_32x32x16_bf16(kt1a, qf[1], s_a, 0, 0, 0);
        __builtin_amdgcn_s_setprio(0);

        // ---- SM_a: trans-pipe exp + pack + permlane ----
        uint32_t ua[8];
        #pragma unroll
        for (int i = 0; i < 8; ++i) {
            f32x2 e01;
            ua[i] = fexp2_pk(s_a[2*i], s_a[2*i+1], e01);
            if (i & 1) lacc1 += e01; else lacc0 += e01;
        }
        short8 pfa0, pfa1;
        PMERGE(ua, pfa0, pfa1)

        // ---- QK kb=1 (issued early; executes under SM_a tail / PV_a head) ----
        short8 kt0b = *(const short8*)(&kt_lds[buf][2*512 + lane*8]);
        short8 kt1b = *(const short8*)(&kt_lds[buf][3*512 + lane*8]);
        f32x16 s_b = (f32x16)(0.f);
        s_b = __builtin_amdgcn_mfma_f32_32x32x16_bf16(kt0b, qf[0], s_b, 0, 0, 0);
        s_b = __builtin_amdgcn_mfma_f32_32x32x16_bf16(kt1b, qf[1], s_b, 0, 0, 0);

        // ---- fence-free region: SM_b trans/VALU interleaves with PV_a MFMA ----
        uint32_t ub[8];
        #pragma unroll
        for (int i = 0; i < 8; ++i) {
            f32x2 e01;
            ub[i] = fexp2_pk(s_b[2*i], s_b[2*i+1], e01);
            if (i & 1) lacc1 += e01; else lacc0 += e01;
        }
        #pragma unroll
        for (int msub = 0; msub < 2; ++msub) {     // PV_a: keys [0,32)
            short8 pfm = msub ? pfa1 : pfa0;
            int ks16 = msub;
            #pragma unroll
            for (int cfr = 0; cfr < 4; ++cfr) {
                short8 vf = *(const short8*)(&v_lds[buf][(cfr*4 + ks16)*512 + lane*8]);
                acc[cfr] = __builtin_amdgcn_mfma_f32_32x32x16_bf16(vf, pfm, acc[cfr], 0, 0, 0);
            }
        }
        short8 pfb0, pfb1;
        PMERGE(ub, pfb0, pfb1)

        // ---- PV_b (tail cluster, prio-boosted) ----
        __builtin_amdgcn_s_setprio(1);
        #pragma unroll
        for (int msub = 0; msub < 2; ++msub) {     // keys [32,64)
            short8 pfm = msub ? pfb1 : pfb0;
            int ks16 = 2 + msub;
            #pragma unroll
            for (int cfr = 0; cfr < 4; ++cfr) {
                short8 vf = *(const short8*)(&v_lds[buf][(cfr*4 + ks16)*512 + lane*8]);
                acc[cfr] = __builtin_amdgcn_mfma_f32_32x32x16_bf16(vf, pfm, acc[cfr], 0, 0, 0);
            }
        }
        __builtin_amdgcn_s_setprio(0);

        __syncthreads();
        buf ^= 1;
    }

    // finalize l: horizontal + other lane-half's key contributions
    f32x2 lacc = lacc0 + lacc1;
    float lsum = lacc.x + lacc.y;
    {
        union { float f; int i; } cv; cv.f = lsum;
        cv.i = __shfl_xor(cv.i, 32);
        lsum += cv.f;
    }
    if (cs == 0 && h == 0)
        lpart[(size_t)(ms*B_ + b)*HW_ + qb*256 + w*32 + l31] = lsum;

    // pacc raw fragment dump: contiguous 2KB per cfr wave-store
    int blkl = ((ms*B_ + b)*16 + qb)*2 + cs;
    #pragma unroll
    for (int cfr = 0; cfr < 4; ++cfr) {
        union { uint32_t d[8]; us8 hlf[2]; } pk;
        #pragma unroll
        for (int i = 0; i < 8; ++i)
            pk.d[i] = pktr(acc[cfr][2*i], acc[cfr][2*i+1]);
        ushort* dst = pacc + ((size_t)(blkl*32 + w*4 + cfr) << 10);
        *(us8*)(dst + lane*8)       = pk.hlf[0];
        *(us8*)(dst + 512 + lane*8) = pk.hlf[1];
    }
    #undef STAGE
    #undef PMERGE
}

// ---------------- kernel 4: combine via LDS transpose + epilogue ----------
// grid = 1024 blocks (b,qb,cs,w), 256 thr. Byte-identical to R8.
__global__ __launch_bounds__(256) void k_comb(
    const ushort* __restrict__ pacc, const float* __restrict__ lpart,
    const float* __restrict__ x, const float* __restrict__ gamma_p,
    float* __restrict__ out)
{
    __shared__ float lds_acc[128*36];   // 18.4 KB

    int blk = blockIdx.x;
    int w  = blk & 7;
    int cs = (blk >> 3) & 1;
    int qb = (blk >> 4) & 15;
    int b  = blk >> 8;
    int t = threadIdx.x;

    int l31 = t & 31;
    int h   = (t >> 5) & 1;
    int cfr = (t >> 6) & 3;
    int q = qb*256 + w*32 + l31;
    int lanef = h*32 + l31;

    float sum[16];
    #pragma unroll
    for (int k = 0; k < 16; ++k) sum[k] = 0.f;
    float lt = 0.f;

    #pragma unroll
    for (int ms = 0; ms < MS_; ++ms) {
        int blkl = ((ms*B_ + b)*16 + qb)*2 + cs;
        const ushort* pp = pacc + ((size_t)(blkl*32 + w*4 + cfr) << 10) + lanef*8;
        us8 a0 = *(const us8*)pp;
        us8 a1 = *(const us8*)(pp + 512);
        #pragma unroll
        for (int k = 0; k < 8; ++k) {
            union { uint32_t u; float f; } cv;
            cv.u = ((uint32_t)a0[k]) << 16;  sum[k]   += cv.f;
            cv.u = ((uint32_t)a1[k]) << 16;  sum[k+8] += cv.f;
        }
        lt += lpart[(size_t)(ms*B_ + b)*HW_ + q];
    }

    float rl = gamma_p[0] / lt;
    #pragma unroll
    for (int k = 0; k < 16; ++k) {
        int c = cfr*32 + (k & 3) + 8*(k >> 2) + 4*h;
        lds_acc[c*36 + l31] = sum[k]*rl;
    }
    __syncthreads();

    // phase 2: 1024 float4 slots [c(128)][qg(8)]; thread does 4 slots
    const float* xb = x + ((size_t)(b*C_ + cs*128))*HW_ + qb*256 + w*32;
    float* ob = out + ((size_t)(b*C_ + cs*128))*HW_ + qb*256 + w*32;
    #pragma unroll
    for (int i = 0; i < 4; ++i) {
        int s = t + i*256;
        int c = s >> 3, qg = s & 7;
        float4 a = *(const float4*)(&lds_acc[c*36 + qg*4]);
        size_t off = (size_t)c*HW_ + qg*4;
        float4 xv = *(const float4*)(xb + off);
        a.x += xv.x; a.y += xv.y; a.z += xv.z; a.w += xv.w;
        *(float4*)(ob + off) = a;
    }
}

extern "C" void kernel_launch(void* const* d_in, const int* in_sizes, int n_in,
                              void* d_out, int out_size, void* d_ws, size_t ws_size,
                              hipStream_t stream)
{
    const float* x      = (const float*)d_in[0];
    const float* conv_w = (const float*)d_in[1];
    const float* conv_b = (const float*)d_in[2];
    const float* q_w    = (const float*)d_in[3];
    const float* q_b    = (const float*)d_in[4];
    const float* k_w    = (const float*)d_in[5];
    const float* k_b    = (const float*)d_in[6];
    const float* v_w    = (const float*)d_in[7];
    const float* v_b    = (const float*)d_in[8];
    const float* gamma  = (const float*)d_in[9];
    float* out = (float*)d_out;

    char* ws = (char*)d_ws;
    ushort* wbf   = (ushort*)(ws + WT_OFF);
    float*  ball  = (float*)(ws + BALL_OFF);
    ushort* qg    = (ushort*)(ws + Q_OFF);
    ushort* ktg   = (ushort*)(ws + KT_OFF);
    ushort* vg    = (ushort*)(ws + V_OFF);
    ushort* pacc  = (ushort*)(ws + PACC_OFF);
    float*  lpart = (float*)(ws + LPART_OFF);

    k_setup<<<ROWS_, 256, 0, stream>>>(conv_w, conv_b, q_w, q_b, k_w, k_b,
                                       v_w, v_b, wbf, ball);
    k_qkv<<<B_*128, 320, 0, stream>>>(x, wbf, ball, qg, ktg, vg);
    k_attn<<<512, 512, 0, stream>>>(qg, ktg, vg, pacc, lpart);
    k_comb<<<1024, 256, 0, stream>>>(pacc, lpart, x, gamma, out);
}